// Round 14
// baseline (65.173 us; speedup 1.0000x reference)
//
#include <hip/hip_runtime.h>

#define NB 64
#define NT 1024
#define NA 512
#define NF 32
#define KW 31
#define PADW 15
#define TC 64                      // t's per block
#define CWN (2 * KW * NF)          // 1984 floats of transposed conv weights

typedef __fp16 half2v __attribute__((ext_vector_type(2)));

__device__ __forceinline__ float fast_tanh(float x) {
    float e = __builtin_amdgcn_exp2f(x * 2.885390081777927f);
    return 1.0f - 2.0f * __builtin_amdgcn_rcpf(1.0f + e);
}
__device__ __forceinline__ float fast_sigmoid(float u) {
    return __builtin_amdgcn_rcpf(1.0f + __builtin_amdgcn_exp2f(-u * 1.4426950408889634f));
}
__device__ __forceinline__ unsigned pkrtz(float a, float b) {
    half2v h = __builtin_amdgcn_cvt_pkrtz(a, b);
    return __builtin_bit_cast(unsigned, h);
}
__device__ __forceinline__ float fdot2u(unsigned cv, unsigned lw, float acc) {
#if __has_builtin(__builtin_amdgcn_fdot2)
    return __builtin_amdgcn_fdot2(__builtin_bit_cast(half2v, cv),
                                  __builtin_bit_cast(half2v, lw), acc, false);
#else
    half2v a = __builtin_bit_cast(half2v, cv), b = __builtin_bit_cast(half2v, lw);
    return acc + (float)a.x * (float)b.x + (float)a.y * (float)b.y;
#endif
}

// ---------------- kernel A: pq = query @ W_w^T + W_b (coalesced row-per-wave GEMV)
__global__ __launch_bounds__(256) void lsa_pq(
    const float* __restrict__ query, const float* __restrict__ Ww,
    const float* __restrict__ Wb, const float* __restrict__ convw,
    float* __restrict__ pq, float* __restrict__ cwT)
{
    if (blockIdx.x == 0) {
        for (int i = threadIdx.x; i < NF * 2 * KW; i += 256) {
            int f = i / (2 * KW);
            int r = i - f * 2 * KW;
            int c = r / KW;
            int k = r - c * KW;
            cwT[(c * KW + k) * NF + f] = convw[i];   // [c][k][f]
        }
    }
    __shared__ float qs[NA];
    int tid  = threadIdx.x;
    int lane = tid & 63;
    int wv   = tid >> 6;
    int b     = blockIdx.x >> 3;
    int chunk = blockIdx.x & 7;
    qs[tid]       = query[b * NA + tid];
    qs[tid + 256] = query[b * NA + tid + 256];
    __syncthreads();

    float4 q0 = *(const float4*)(qs + 8 * lane);
    float4 q1 = *(const float4*)(qs + 8 * lane + 4);
#pragma unroll 4
    for (int i = 0; i < 16; ++i) {
        int a = chunk * 64 + wv * 16 + i;
        const float4* wr = (const float4*)(Ww + (long)a * NA + 8 * lane);
        float4 w0 = wr[0], w1 = wr[1];
        float s = w0.x * q0.x + w0.y * q0.y + w0.z * q0.z + w0.w * q0.w
                + w1.x * q1.x + w1.y * q1.y + w1.z * q1.z + w1.w * q1.w;
#pragma unroll
        for (int m = 1; m <= 32; m <<= 1) s += __shfl_xor(s, m, 64);
        if (lane == 0) pq[b * NA + a] = s + Wb[a];
    }
}

// ---------------- kernel B (hot): s = sigmoid(u) -> d_out
// 1024 blocks = 4/CU. Thread owns 4 consecutive a's; waves 0,1 handle tt 0..31,
// waves 2,3 handle tt 32..63 (halves the cv LDS-broadcast traffic vs 2-a design).
__global__ __launch_bounds__(256, 4) void lsa_main(
    const float* __restrict__ enc, const float* __restrict__ cum,
    const float* __restrict__ att, const float* __restrict__ cwT,
    const float* __restrict__ Lw, const float* __restrict__ Lb,
    const float* __restrict__ vw, const float* __restrict__ pq,
    float* __restrict__ sout)
{
    __shared__ float cw_s[CWN];            // conv weights [c][k][f], 7.75 KB
    __shared__ float cum_s[TC + 30];
    __shared__ float att_s[TC + 30];
    __shared__ unsigned cvsh[TC][20];      // f16x2 conv output, 80B row stride
    __shared__ float wred[4][34];          // per-wave tt sums (32 used)

    int tid  = threadIdx.x;
    int lane = tid & 63;
    int wv   = tid >> 6;
    int b    = blockIdx.x >> 4;            // NT/TC = 16 chunks
    int t0   = (blockIdx.x & 15) * TC;

    // ---- stage conv weights into LDS (coalesced float4 copy)
    {
        const float4* src = (const float4*)cwT;
        float4* dst = (float4*)cw_s;
        if (tid < 248) {
            dst[tid]       = src[tid];
            dst[tid + 248] = src[tid + 248];
        }
    }
    // ---- stage cum/att slice (with halo)
    if (tid < TC + 30) {
        int t = t0 - PADW + tid;
        bool ok = (t >= 0) && (t < NT);
        cum_s[tid] = ok ? cum[b * NT + t] : 0.f;
        att_s[tid] = ok ? att[b * NT + t] : 0.f;
    }

    // ---- per-thread constants: 4 a's, packed SEQUENTIALLY per a (no reg spike)
    int a0  = (tid & 127) * 4;             // 128 threads span a 0..511
    int tth = tid >> 7;                    // 0: tt 0..31, 1: tt 32..63
    unsigned h[4][16];
    float c4[4], v4[4];
#pragma unroll
    for (int ai = 0; ai < 4; ++ai) {
        const float4* lp = (const float4*)(Lw + (long)(a0 + ai) * NF);
#pragma unroll
        for (int i = 0; i < 8; ++i) {
            float4 w = lp[i];
            h[ai][2 * i]     = pkrtz(w.x, w.y);
            h[ai][2 * i + 1] = pkrtz(w.z, w.w);
        }
        c4[ai] = pq[b * NA + a0 + ai] + Lb[a0 + ai];
        v4[ai] = vw[a0 + ai];
    }
    __syncthreads();

    // ---- conv phase: wave wv computes filters [8wv, 8wv+8) for tt = lane (all 64)
    {
        int tt  = lane;
        int fbu = wv * 8;
        float acc[8] = {0, 0, 0, 0, 0, 0, 0, 0};
#pragma unroll
        for (int k = 0; k < KW; ++k) {
            float x0 = cum_s[tt + k];
            float x1 = att_s[tt + k];
            const float4* A  = (const float4*)(cw_s + k * NF + fbu);
            const float4* Bv = (const float4*)(cw_s + (KW + k) * NF + fbu);
#pragma unroll
            for (int j = 0; j < 2; ++j) {
                float4 wa = A[j], wb = Bv[j];
                acc[4 * j + 0] = fmaf(x0, wa.x, fmaf(x1, wb.x, acc[4 * j + 0]));
                acc[4 * j + 1] = fmaf(x0, wa.y, fmaf(x1, wb.y, acc[4 * j + 1]));
                acc[4 * j + 2] = fmaf(x0, wa.z, fmaf(x1, wb.z, acc[4 * j + 2]));
                acc[4 * j + 3] = fmaf(x0, wa.w, fmaf(x1, wb.w, acc[4 * j + 3]));
            }
        }
        uint4 pk;
        pk.x = pkrtz(acc[0], acc[1]);
        pk.y = pkrtz(acc[2], acc[3]);
        pk.z = pkrtz(acc[4], acc[5]);
        pk.w = pkrtz(acc[6], acc[7]);
        *(uint4*)&cvsh[tt][wv * 4] = pk;
    }
    __syncthreads();

#define DOA(ai, ecomp)                                                  \
    {                                                                   \
        float y0 = 0.f, y1 = 0.f;                                       \
        y0 = fdot2u(cva.x, h[ai][0],  y0); y1 = fdot2u(cva.y, h[ai][1],  y1); \
        y0 = fdot2u(cva.z, h[ai][2],  y0); y1 = fdot2u(cva.w, h[ai][3],  y1); \
        y0 = fdot2u(cvb.x, h[ai][4],  y0); y1 = fdot2u(cvb.y, h[ai][5],  y1); \
        y0 = fdot2u(cvb.z, h[ai][6],  y0); y1 = fdot2u(cvb.w, h[ai][7],  y1); \
        y0 = fdot2u(cvc.x, h[ai][8],  y0); y1 = fdot2u(cvc.y, h[ai][9],  y1); \
        y0 = fdot2u(cvc.z, h[ai][10], y0); y1 = fdot2u(cvc.w, h[ai][11], y1); \
        y0 = fdot2u(cvd.x, h[ai][12], y0); y1 = fdot2u(cvd.y, h[ai][13], y1); \
        y0 = fdot2u(cvd.z, h[ai][14], y0); y1 = fdot2u(cvd.w, h[ai][15], y1); \
        s = fmaf(fast_tanh(y0 + y1 + c4[ai] + (ecomp)), v4[ai], s);     \
    }

    // ---- main loop: this thread's 32 tt in 4 groups of 8; 4 a's per thread
    const float* erow = enc + ((long)b * NT + t0 + tth * 32) * NA + a0;
#pragma unroll 1
    for (int g = 0; g < 4; ++g) {
        float p[8];
#pragma unroll
        for (int j = 0; j < 8; ++j) {
            int tt  = g * 8 + j;               // 0..31 within this tth half
            int gtt = tth * 32 + tt;           // cvsh row
            float4 e = *(const float4*)(erow + (long)tt * NA);
            uint4 cva = *(const uint4*)&cvsh[gtt][0];
            uint4 cvb = *(const uint4*)&cvsh[gtt][4];
            uint4 cvc = *(const uint4*)&cvsh[gtt][8];
            uint4 cvd = *(const uint4*)&cvsh[gtt][12];
            float s = 0.f;
            DOA(0, e.x)
            DOA(1, e.y)
            DOA(2, e.z)
            DOA(3, e.w)
            p[j] = s;
        }

        // register butterfly transpose-reduce over 8 tt (lane bits 0..2)
        {
            int len = 8;
#pragma unroll
            for (int m = 1; m <= 4; m <<= 1) {
                int hlen = len >> 1;
                bool up = (lane & m) != 0;
#pragma unroll
                for (int i = 0; i < 4; ++i) {
                    if (i < hlen) {
                        float send = up ? p[i] : p[i + hlen];
                        float keep = up ? p[i + hlen] : p[i];
                        p[i] = keep + __shfl_xor(send, m, 64);
                    }
                }
                len = hlen;
            }
            float v = p[0];
            v += __shfl_xor(v, 8, 64);
            v += __shfl_xor(v, 16, 64);
            v += __shfl_xor(v, 32, 64);
            int l3 = lane & 7;
            int tt = ((l3 & 1) << 2) | (l3 & 2) | ((l3 & 4) >> 2);
            if (lane < 8) wred[wv][g * 8 + tt] = v;
        }
    }
#undef DOA
    __syncthreads();
    if (tid < TC) {
        float u = (tid < 32) ? (wred[0][tid] + wred[1][tid])
                             : (wred[2][tid - 32] + wred[3][tid - 32]);
        sout[b * NT + t0 + tid] = fast_sigmoid(u);
    }
}

// ---------------- kernel C: normalize with alpha recursion + mask (in place)
__global__ __launch_bounds__(256) void lsa_norm(
    const float* __restrict__ alpha, const int* __restrict__ plen,
    float* __restrict__ out)
{
    __shared__ float red[4];
    int tid = threadIdx.x;
    int b = blockIdx.x;
    int pl = plen[b];
    float w[4];
    float psum = 0.f;
#pragma unroll
    for (int j = 0; j < 4; ++j) {
        int t = tid + 256 * j;
        float s   = out[b * NT + t];
        float al  = alpha[b * NT + t];
        float am1 = (t >= 1) ? alpha[b * NT + t - 1] : 0.f;
        float am2 = (t >= 2) ? alpha[b * NT + t - 2] : 0.f;
        float val = (t < pl) ? (al + am1 + am2 + 1e-7f) * s : 0.f;
        w[j] = val;
        psum += val;
    }
#pragma unroll
    for (int m = 32; m >= 1; m >>= 1) psum += __shfl_xor(psum, m, 64);
    int lane = tid & 63, wid = tid >> 6;
    if (lane == 0) red[wid] = psum;
    __syncthreads();
    float total = red[0] + red[1] + red[2] + red[3];
    float inv = 1.0f / total;
#pragma unroll
    for (int j = 0; j < 4; ++j) {
        int t = tid + 256 * j;
        out[b * NT + t] = w[j] * inv;
    }
}

extern "C" void kernel_launch(void* const* d_in, const int* in_sizes, int n_in,
                              void* d_out, int out_size, void* d_ws, size_t ws_size,
                              hipStream_t stream)
{
    const float* enc   = (const float*)d_in[0];
    const float* query = (const float*)d_in[1];
    const float* cum   = (const float*)d_in[2];
    const float* att   = (const float*)d_in[3];
    const float* alpha = (const float*)d_in[4];
    const float* convw = (const float*)d_in[5];
    const float* Lw    = (const float*)d_in[6];
    const float* Lb    = (const float*)d_in[7];
    const float* Ww    = (const float*)d_in[8];
    const float* Wb    = (const float*)d_in[9];
    const float* vw    = (const float*)d_in[10];
    const int*   plen  = (const int*)d_in[12];

    float* pq  = (float*)d_ws;                       // 64*512 floats = 128 KB
    float* cwT = (float*)d_ws + NB * NA;             // 1984 floats
    float* sout = (float*)d_out;

    lsa_pq  <<<NB * 8,         256, 0, stream>>>(query, Ww, Wb, convw, pq, cwT);
    lsa_main<<<NB * (NT / TC), 256, 0, stream>>>(enc, cum, att, cwT, Lw, Lb, vw, pq, sout);
    lsa_norm<<<NB,             256, 0, stream>>>(alpha, plen, sout);
}

// Round 15
// 57.360 us; speedup vs baseline: 1.1362x; 1.1362x over previous
//
#include <hip/hip_runtime.h>

#define NB 64
#define NT 1024
#define NA 512
#define NF 32
#define KW 31
#define PADW 15
#define TC 64                      // t's per block
#define CWN (2 * KW * NF)          // 1984 floats of transposed conv weights

typedef __fp16 half2v __attribute__((ext_vector_type(2)));

__device__ __forceinline__ float fast_tanh(float x) {
    float e = __builtin_amdgcn_exp2f(x * 2.885390081777927f);
    return 1.0f - 2.0f * __builtin_amdgcn_rcpf(1.0f + e);
}
__device__ __forceinline__ float fast_sigmoid(float u) {
    return __builtin_amdgcn_rcpf(1.0f + __builtin_amdgcn_exp2f(-u * 1.4426950408889634f));
}
__device__ __forceinline__ unsigned pkrtz(float a, float b) {
    half2v h = __builtin_amdgcn_cvt_pkrtz(a, b);
    return __builtin_bit_cast(unsigned, h);
}
__device__ __forceinline__ float fdot2u(unsigned cv, unsigned lw, float acc) {
#if __has_builtin(__builtin_amdgcn_fdot2)
    return __builtin_amdgcn_fdot2(__builtin_bit_cast(half2v, cv),
                                  __builtin_bit_cast(half2v, lw), acc, false);
#else
    half2v a = __builtin_bit_cast(half2v, cv), b = __builtin_bit_cast(half2v, lw);
    return acc + (float)a.x * (float)b.x + (float)a.y * (float)b.y;
#endif
}

// ---------------- kernel A: pq = query @ W_w^T + W_b (coalesced row-per-wave GEMV)
__global__ __launch_bounds__(256) void lsa_pq(
    const float* __restrict__ query, const float* __restrict__ Ww,
    const float* __restrict__ Wb, const float* __restrict__ convw,
    float* __restrict__ pq, float* __restrict__ cwT)
{
    if (blockIdx.x == 0) {
        for (int i = threadIdx.x; i < NF * 2 * KW; i += 256) {
            int f = i / (2 * KW);
            int r = i - f * 2 * KW;
            int c = r / KW;
            int k = r - c * KW;
            cwT[(c * KW + k) * NF + f] = convw[i];   // [c][k][f]
        }
    }
    __shared__ float qs[NA];
    int tid  = threadIdx.x;
    int lane = tid & 63;
    int wv   = tid >> 6;
    int b     = blockIdx.x >> 3;
    int chunk = blockIdx.x & 7;
    qs[tid]       = query[b * NA + tid];
    qs[tid + 256] = query[b * NA + tid + 256];
    __syncthreads();

    float4 q0 = *(const float4*)(qs + 8 * lane);
    float4 q1 = *(const float4*)(qs + 8 * lane + 4);
#pragma unroll 4
    for (int i = 0; i < 16; ++i) {
        int a = chunk * 64 + wv * 16 + i;
        const float4* wr = (const float4*)(Ww + (long)a * NA + 8 * lane);
        float4 w0 = wr[0], w1 = wr[1];
        float s = w0.x * q0.x + w0.y * q0.y + w0.z * q0.z + w0.w * q0.w
                + w1.x * q1.x + w1.y * q1.y + w1.z * q1.z + w1.w * q1.w;
#pragma unroll
        for (int m = 1; m <= 32; m <<= 1) s += __shfl_xor(s, m, 64);
        if (lane == 0) pq[b * NA + a] = s + Wb[a];
    }
}

// ---------------- kernel B (hot): s = sigmoid(u) -> d_out
// 1024 blocks = 4/CU. Thread owns a = 2*tid, 2*tid+1 for 64 t's.
// Software-pipelined: cv quads prefetched 1 tt ahead, enc 4 tt ahead.
__global__ __launch_bounds__(256, 4) void lsa_main(
    const float* __restrict__ enc, const float* __restrict__ cum,
    const float* __restrict__ att, const float* __restrict__ cwT,
    const float* __restrict__ Lw, const float* __restrict__ Lb,
    const float* __restrict__ vw, const float* __restrict__ pq,
    float* __restrict__ sout)
{
    __shared__ float cw_s[CWN];            // conv weights [c][k][f], 7.75 KB
    __shared__ float cum_s[TC + 30];
    __shared__ float att_s[TC + 30];
    __shared__ unsigned cvsh[TC][20];      // f16x2 conv output, 80B row stride
    __shared__ float wred[4][TC + 2];      // per-wave tt sums

    int tid  = threadIdx.x;
    int lane = tid & 63;
    int wv   = tid >> 6;
    int b    = blockIdx.x >> 4;            // NT/TC = 16 chunks
    int t0   = (blockIdx.x & 15) * TC;

    // ---- stage conv weights into LDS (coalesced float4 copy)
    {
        const float4* src = (const float4*)cwT;
        float4* dst = (float4*)cw_s;
        if (tid < 248) {
            dst[tid]       = src[tid];
            dst[tid + 248] = src[tid + 248];
        }
    }
    // ---- stage cum/att slice (with halo)
    if (tid < TC + 30) {
        int t = t0 - PADW + tid;
        bool ok = (t >= 0) && (t < NT);
        cum_s[tid] = ok ? cum[b * NT + t] : 0.f;
        att_s[tid] = ok ? att[b * NT + t] : 0.f;
    }

    // ---- per-thread constants: pack L_w rows to f16x2 as they arrive
    int a0 = 2 * tid;
    const float4* lp = (const float4*)(Lw + (long)a0 * NF);
    unsigned h0[16], h1[16];
#pragma unroll
    for (int i = 0; i < 8; ++i) {
        float4 wa = lp[i];
        float4 wb = lp[8 + i];
        h0[2 * i]     = pkrtz(wa.x, wa.y);
        h0[2 * i + 1] = pkrtz(wa.z, wa.w);
        h1[2 * i]     = pkrtz(wb.x, wb.y);
        h1[2 * i + 1] = pkrtz(wb.z, wb.w);
    }
    float c0 = pq[b * NA + a0]     + Lb[a0];
    float c1 = pq[b * NA + a0 + 1] + Lb[a0 + 1];
    float vx = vw[a0], vy = vw[a0 + 1];
    __syncthreads();

    // ---- conv phase: wave wv computes filters [8wv, 8wv+8) for tt = lane (all 64)
    {
        int tt  = lane;
        int fbu = wv * 8;
        float acc[8] = {0, 0, 0, 0, 0, 0, 0, 0};
#pragma unroll
        for (int k = 0; k < KW; ++k) {
            float x0 = cum_s[tt + k];
            float x1 = att_s[tt + k];
            const float4* A  = (const float4*)(cw_s + k * NF + fbu);
            const float4* Bv = (const float4*)(cw_s + (KW + k) * NF + fbu);
#pragma unroll
            for (int j = 0; j < 2; ++j) {
                float4 wa = A[j], wb = Bv[j];
                acc[4 * j + 0] = fmaf(x0, wa.x, fmaf(x1, wb.x, acc[4 * j + 0]));
                acc[4 * j + 1] = fmaf(x0, wa.y, fmaf(x1, wb.y, acc[4 * j + 1]));
                acc[4 * j + 2] = fmaf(x0, wa.z, fmaf(x1, wb.z, acc[4 * j + 2]));
                acc[4 * j + 3] = fmaf(x0, wa.w, fmaf(x1, wb.w, acc[4 * j + 3]));
            }
        }
        uint4 pk;
        pk.x = pkrtz(acc[0], acc[1]);
        pk.y = pkrtz(acc[2], acc[3]);
        pk.z = pkrtz(acc[4], acc[5]);
        pk.w = pkrtz(acc[6], acc[7]);
        *(uint4*)&cvsh[tt][wv * 4] = pk;
    }
    __syncthreads();

    // ---- main loop: 4 passes of 16 tt, software-pipelined
    const float* erow = enc + ((long)b * NT + t0) * NA + a0;
#pragma unroll 1
    for (int pass = 0; pass < 4; ++pass) {
        const int base = pass * 16;
        float p[16];
        float2 earr[4];
#pragma unroll
        for (int i = 0; i < 4; ++i)
            earr[i] = *(const float2*)(erow + (long)(base + i) * NA);
        uint4 ca = *(const uint4*)&cvsh[base][0];
        uint4 cb = *(const uint4*)&cvsh[base][4];
        uint4 cc = *(const uint4*)&cvsh[base][8];
        uint4 cd = *(const uint4*)&cvsh[base][12];

#pragma unroll
        for (int j = 0; j < 16; ++j) {
            // prefetch next tt's cv quads (LDS) and enc 4 ahead (global)
            uint4 na, nb, nc, nd;
            if (j < 15) {
                na = *(const uint4*)&cvsh[base + j + 1][0];
                nb = *(const uint4*)&cvsh[base + j + 1][4];
                nc = *(const uint4*)&cvsh[base + j + 1][8];
                nd = *(const uint4*)&cvsh[base + j + 1][12];
            }
            float2 ne;
            if (j + 4 < 16)
                ne = *(const float2*)(erow + (long)(base + j + 4) * NA);

            float x0[2] = {0.f, 0.f};
            float x1[2] = {0.f, 0.f};
            x0[0] = fdot2u(ca.x, h0[0],  x0[0]); x0[1] = fdot2u(cb.x, h0[4],  x0[1]);
            x0[0] = fdot2u(ca.y, h0[1],  x0[0]); x0[1] = fdot2u(cb.y, h0[5],  x0[1]);
            x0[0] = fdot2u(ca.z, h0[2],  x0[0]); x0[1] = fdot2u(cb.z, h0[6],  x0[1]);
            x0[0] = fdot2u(ca.w, h0[3],  x0[0]); x0[1] = fdot2u(cb.w, h0[7],  x0[1]);
            x1[0] = fdot2u(ca.x, h1[0],  x1[0]); x1[1] = fdot2u(cb.x, h1[4],  x1[1]);
            x1[0] = fdot2u(ca.y, h1[1],  x1[0]); x1[1] = fdot2u(cb.y, h1[5],  x1[1]);
            x1[0] = fdot2u(ca.z, h1[2],  x1[0]); x1[1] = fdot2u(cb.z, h1[6],  x1[1]);
            x1[0] = fdot2u(ca.w, h1[3],  x1[0]); x1[1] = fdot2u(cb.w, h1[7],  x1[1]);
            x0[0] = fdot2u(cc.x, h0[8],  x0[0]); x0[1] = fdot2u(cd.x, h0[12], x0[1]);
            x0[0] = fdot2u(cc.y, h0[9],  x0[0]); x0[1] = fdot2u(cd.y, h0[13], x0[1]);
            x0[0] = fdot2u(cc.z, h0[10], x0[0]); x0[1] = fdot2u(cd.z, h0[14], x0[1]);
            x0[0] = fdot2u(cc.w, h0[11], x0[0]); x0[1] = fdot2u(cd.w, h0[15], x0[1]);
            x1[0] = fdot2u(cc.x, h1[8],  x1[0]); x1[1] = fdot2u(cd.x, h1[12], x1[1]);
            x1[0] = fdot2u(cc.y, h1[9],  x1[0]); x1[1] = fdot2u(cd.y, h1[13], x1[1]);
            x1[0] = fdot2u(cc.z, h1[10], x1[0]); x1[1] = fdot2u(cd.z, h1[14], x1[1]);
            x1[0] = fdot2u(cc.w, h1[11], x1[0]); x1[1] = fdot2u(cd.w, h1[15], x1[1]);

            float2 e = earr[j & 3];
            p[j] = fast_tanh(x0[0] + x0[1] + c0 + e.x) * vx
                 + fast_tanh(x1[0] + x1[1] + c1 + e.y) * vy;

            if (j + 4 < 16) earr[j & 3] = ne;
            if (j < 15) { ca = na; cb = nb; cc = nc; cd = nd; }
        }

        // register butterfly transpose-reduce over 16 tt (lane bits 0..3)
        {
            int len = 16;
#pragma unroll
            for (int m = 1; m <= 8; m <<= 1) {
                int hlen = len >> 1;
                bool up = (lane & m) != 0;
#pragma unroll
                for (int i = 0; i < 8; ++i) {
                    if (i < hlen) {
                        float send = up ? p[i] : p[i + hlen];
                        float keep = up ? p[i + hlen] : p[i];
                        p[i] = keep + __shfl_xor(send, m, 64);
                    }
                }
                len = hlen;
            }
            float v = p[0] + __shfl_xor(p[0], 16, 64);
            v = v + __shfl_xor(v, 32, 64);
            int l4 = lane & 15;
            int tt = ((l4 & 1) << 3) | ((l4 & 2) << 1) | ((l4 & 4) >> 1) | ((l4 & 8) >> 3);
            if (lane < 16) wred[wv][base + tt] = v;
        }
    }
    __syncthreads();
    if (tid < TC) {
        float u = wred[0][tid] + wred[1][tid] + wred[2][tid] + wred[3][tid];
        sout[b * NT + t0 + tid] = fast_sigmoid(u);
    }
}

// ---------------- kernel C: normalize with alpha recursion + mask (in place)
__global__ __launch_bounds__(256) void lsa_norm(
    const float* __restrict__ alpha, const int* __restrict__ plen,
    float* __restrict__ out)
{
    __shared__ float red[4];
    int tid = threadIdx.x;
    int b = blockIdx.x;
    int pl = plen[b];
    float w[4];
    float psum = 0.f;
#pragma unroll
    for (int j = 0; j < 4; ++j) {
        int t = tid + 256 * j;
        float s   = out[b * NT + t];
        float al  = alpha[b * NT + t];
        float am1 = (t >= 1) ? alpha[b * NT + t - 1] : 0.f;
        float am2 = (t >= 2) ? alpha[b * NT + t - 2] : 0.f;
        float val = (t < pl) ? (al + am1 + am2 + 1e-7f) * s : 0.f;
        w[j] = val;
        psum += val;
    }
#pragma unroll
    for (int m = 32; m >= 1; m >>= 1) psum += __shfl_xor(psum, m, 64);
    int lane = tid & 63, wid = tid >> 6;
    if (lane == 0) red[wid] = psum;
    __syncthreads();
    float total = red[0] + red[1] + red[2] + red[3];
    float inv = 1.0f / total;
#pragma unroll
    for (int j = 0; j < 4; ++j) {
        int t = tid + 256 * j;
        out[b * NT + t] = w[j] * inv;
    }
}

extern "C" void kernel_launch(void* const* d_in, const int* in_sizes, int n_in,
                              void* d_out, int out_size, void* d_ws, size_t ws_size,
                              hipStream_t stream)
{
    const float* enc   = (const float*)d_in[0];
    const float* query = (const float*)d_in[1];
    const float* cum   = (const float*)d_in[2];
    const float* att   = (const float*)d_in[3];
    const float* alpha = (const float*)d_in[4];
    const float* convw = (const float*)d_in[5];
    const float* Lw    = (const float*)d_in[6];
    const float* Lb    = (const float*)d_in[7];
    const float* Ww    = (const float*)d_in[8];
    const float* Wb    = (const float*)d_in[9];
    const float* vw    = (const float*)d_in[10];
    const int*   plen  = (const int*)d_in[12];

    float* pq  = (float*)d_ws;                       // 64*512 floats = 128 KB
    float* cwT = (float*)d_ws + NB * NA;             // 1984 floats
    float* sout = (float*)d_out;

    lsa_pq  <<<NB * 8,         256, 0, stream>>>(query, Ww, Wb, convw, pq, cwT);
    lsa_main<<<NB * (NT / TC), 256, 0, stream>>>(enc, cum, att, cwT, Lw, Lb, vw, pq, sout);
    lsa_norm<<<NB,             256, 0, stream>>>(alpha, plen, sout);
}